// Round 1
// baseline (657.584 us; speedup 1.0000x reference)
//
#include <hip/hip_runtime.h>
#include <hip/hip_bf16.h>
#include <cstdint>
#include <cstddef>

// Problem constants
#define S_DIM 2048
#define H_DIM 2048
#define NHEAD 16
#define HD_DIM 128
#define O3    6144   // 3*H
#define BS    4096   // B*S
#define NBH   32     // B*NHEAD

typedef short  s16x8  __attribute__((ext_vector_type(8)));
typedef __bf16 bf16x8 __attribute__((ext_vector_type(8)));
typedef float  f32x4  __attribute__((ext_vector_type(4)));

__device__ __forceinline__ unsigned short f2bf(float f) {
  unsigned int b = __float_as_uint(f);
  b += 0x7FFFu + ((b >> 16) & 1u);          // round-to-nearest-even
  return (unsigned short)(b >> 16);
}
__device__ __forceinline__ float bf2f(unsigned short u) {
  return __uint_as_float(((unsigned int)u) << 16);
}
__device__ __forceinline__ bf16x8 load8(const unsigned short* p) {
  s16x8 r = *(const s16x8*)p;
  return __builtin_bit_cast(bf16x8, r);
}
__device__ __forceinline__ f32x4 mfma_bf16(bf16x8 a, bf16x8 b, f32x4 c) {
  return __builtin_amdgcn_mfma_f32_16x16x32_bf16(a, b, c, 0, 0, 0);
}
__device__ __forceinline__ void gload_lds16(const void* g, void* l) {
  __builtin_amdgcn_global_load_lds(
      (__attribute__((address_space(1))) unsigned int*)g,
      (__attribute__((address_space(3))) unsigned int*)l, 16, 0, 0);
}

// ---------------------------------------------------------------- fp32 -> bf16
__global__ void cvt_kernel(const float* __restrict__ src,
                           unsigned short* __restrict__ dst, int n4) {
  int i = blockIdx.x * blockDim.x + threadIdx.x;
  int stride = gridDim.x * blockDim.x;
  for (; i < n4; i += stride) {
    float4 v = ((const float4*)src)[i];
    ushort4 o;
    o.x = f2bf(v.x); o.y = f2bf(v.y); o.z = f2bf(v.z); o.w = f2bf(v.w);
    ((ushort4*)dst)[i] = o;
  }
}

// ---------------------------------------------------------------- RoPE table
__global__ void rope_table_kernel(float* __restrict__ cosT,
                                  float* __restrict__ sinT) {
  int idx = blockIdx.x * blockDim.x + threadIdx.x;   // S_DIM*64 exactly
  int s = idx >> 6, d = idx & 63;
  // inv_freq = theta^(-d/64), theta=10000 -> exp(-(d/64)*ln(10000))
  float inv = expf(-((float)d / 64.0f) * 9.210340371976184f);
  float ang = (float)s * inv;
  float sn, cs;
  sincosf(ang, &sn, &cs);
  cosT[idx] = cs;
  sinT[idx] = sn;
}

// ---------------------------------------------------------------- GEMM (B^T)
// C[M][N] = A[M][K] * Bw[N][K]^T, all bf16 inputs; C fp32 or bf16.
// 128x128 tile, BK=64, 4 waves (2x2), each wave 64x64 = 4x4 16x16x32 frags.
template <bool OUT_BF16>
__global__ __launch_bounds__(256, 2)
void gemm_bt_kernel(const unsigned short* __restrict__ A,
                    const unsigned short* __restrict__ Bw,
                    void* __restrict__ C, int M, int N, int K) {
  __shared__ unsigned short lA[128 * 64];
  __shared__ unsigned short lB[128 * 64];
  const int tid  = threadIdx.x;
  const int wave = tid >> 6, lane = tid & 63;
  const int wy = wave >> 1, wx = wave & 1;
  const int lg = lane >> 4, ll = lane & 15;
  const int m0 = blockIdx.y * 128, n0 = blockIdx.x * 128;

  f32x4 acc[4][4];
#pragma unroll
  for (int i = 0; i < 4; ++i)
#pragma unroll
    for (int j = 0; j < 4; ++j) acc[i][j] = (f32x4){0.f, 0.f, 0.f, 0.f};

  for (int kt = 0; kt < K; kt += 64) {
    if (kt) __syncthreads();
    // stage A-tile and B-tile: 1024 16B chunks each, 256 threads x 4 issues
#pragma unroll
    for (int i = 0; i < 4; ++i) {
      int cb = (i * 4 + wave) * 64;       // wave-uniform chunk base
      int c  = cb + lane;
      int r  = c >> 3, kc = c & 7;
      gload_lds16(A  + (size_t)(m0 + r) * K + kt + kc * 8, &lA[cb * 8]);
      gload_lds16(Bw + (size_t)(n0 + r) * K + kt + kc * 8, &lB[cb * 8]);
    }
    __syncthreads();   // compiler drains vmcnt before s_barrier
#pragma unroll
    for (int kk = 0; kk < 2; ++kk) {
      bf16x8 af[4], bfr[4];
#pragma unroll
      for (int f = 0; f < 4; ++f) {
        af[f]  = load8(&lA[(wy * 64 + f * 16 + ll) * 64 + kk * 32 + lg * 8]);
        bfr[f] = load8(&lB[(wx * 64 + f * 16 + ll) * 64 + kk * 32 + lg * 8]);
      }
#pragma unroll
      for (int fm = 0; fm < 4; ++fm)
#pragma unroll
        for (int fn = 0; fn < 4; ++fn)
          acc[fm][fn] = mfma_bf16(af[fm], bfr[fn], acc[fm][fn]);
    }
  }

  // epilogue: C/D frag layout col = lane&15, row = (lane>>4)*4 + j (m89)
  const int rbase = m0 + wy * 64, cbase = n0 + wx * 64;
#pragma unroll
  for (int fm = 0; fm < 4; ++fm)
#pragma unroll
    for (int fn = 0; fn < 4; ++fn)
#pragma unroll
      for (int j = 0; j < 4; ++j) {
        int r   = rbase + fm * 16 + lg * 4 + j;
        int col = cbase + fn * 16 + ll;
        if (OUT_BF16)
          ((unsigned short*)C)[(size_t)r * N + col] = f2bf(acc[fm][fn][j]);
        else
          ((float*)C)[(size_t)r * N + col] = acc[fm][fn][j];
      }
}

// ---------------------------------------------------------------- RoPE q,k
// mixed[BS][6144] layout: per row, head h at h*384: q[0:128] k[128:256] v[256:384]
// writes q_r/k_r [bh][s][128] with RoPE applied.
__global__ void rope_qk_kernel(const unsigned short* __restrict__ mixed,
                               const float* __restrict__ cosT,
                               const float* __restrict__ sinT,
                               unsigned short* __restrict__ qr,
                               unsigned short* __restrict__ kr) {
  int m = blockIdx.x;              // 0..BS-1
  int s = m & (S_DIM - 1);
  int b = m >> 11;
  const unsigned short* row = mixed + (size_t)m * O3;
#pragma unroll
  for (int it = 0; it < 4; ++it) {
    int idx = it * 256 + threadIdx.x;   // 0..1023 = 16 heads * 64 d-pairs
    int h = idx >> 6, d = idx & 63;
    float c  = cosT[(s << 6) + d];
    float sn = sinT[(s << 6) + d];
    int base = h * 384;
    float q0 = bf2f(row[base + d]),       q1 = bf2f(row[base + 64 + d]);
    float k0 = bf2f(row[base + 128 + d]), k1 = bf2f(row[base + 192 + d]);
    size_t ob = ((size_t)(b * NHEAD + h) * S_DIM + s) * HD_DIM;
    qr[ob + d]      = f2bf(q0 * c - q1 * sn);
    qr[ob + 64 + d] = f2bf(q1 * c + q0 * sn);
    kr[ob + d]      = f2bf(k0 * c - k1 * sn);
    kr[ob + 64 + d] = f2bf(k1 * c + k0 * sn);
  }
}

// ---------------------------------------------------------------- V transpose
// v_t[bh][d][s] <- mixed[b*S+s][h*384+256+d]; 64x64 tiles via LDS.
__global__ __launch_bounds__(256)
void vtrans_kernel(const unsigned short* __restrict__ mixed,
                   unsigned short* __restrict__ vt) {
  __shared__ unsigned short t[64 * 65];
  int st = blockIdx.x, dt = blockIdx.y, bh = blockIdx.z;
  int b = bh >> 4, h = bh & 15;
  int s0 = st * 64, d0 = dt * 64;
  int tid = threadIdx.x;
#pragma unroll
  for (int it = 0; it < 2; ++it) {
    int c = it * 256 + tid;                 // 0..511
    int sl = c >> 3, dc = c & 7;
    const unsigned short* src =
        mixed + (size_t)(b * S_DIM + s0 + sl) * O3 + h * 384 + 256 + d0 + dc * 8;
    s16x8 v = *(const s16x8*)src;
#pragma unroll
    for (int i = 0; i < 8; ++i) t[(dc * 8 + i) * 65 + sl] = (unsigned short)v[i];
  }
  __syncthreads();
#pragma unroll
  for (int it = 0; it < 2; ++it) {
    int c = it * 256 + tid;
    int dl = c >> 3, sc = c & 7;
    s16x8 v;
#pragma unroll
    for (int i = 0; i < 8; ++i) v[i] = (short)t[dl * 65 + sc * 8 + i];
    *(s16x8*)(vt + ((size_t)bh * HD_DIM + d0 + dl) * S_DIM + s0 + sc * 8) = v;
  }
}

// ---------------------------------------------------------------- attention
// grid (qt=32, bh=32), 256 threads = 4 independent waves, 16 q-rows each.
// KV tiles of 32; online softmax; P via per-wave LDS round-trip.
__global__ __launch_bounds__(256)
void attn_kernel(const unsigned short* __restrict__ qr,
                 const unsigned short* __restrict__ kr,
                 const unsigned short* __restrict__ vt,
                 unsigned short* __restrict__ out) {
  __shared__ unsigned short plds[4][16 * 40];  // per-wave P, stride 40 (80B, 16B-aligned)
  const int qt = blockIdx.x, bh = blockIdx.y;
  const int wave = threadIdx.x >> 6, lane = threadIdx.x & 63;
  const int b = bh >> 4, h = bh & 15;
  const int q0 = qt * 64;
  const int qbase = q0 + wave * 16;
  const int lg = lane >> 4, ll = lane & 15;
  const unsigned short* Qb = qr + (size_t)bh * S_DIM * HD_DIM;
  const unsigned short* Kb = kr + (size_t)bh * S_DIM * HD_DIM;
  const unsigned short* Vb = vt + (size_t)bh * HD_DIM * S_DIM;
  const float scale = 0.08838834764831845f;  // 1/sqrt(128)

  bf16x8 aq[4];
#pragma unroll
  for (int kk = 0; kk < 4; ++kk)
    aq[kk] = load8(Qb + (size_t)(qbase + ll) * HD_DIM + kk * 32 + lg * 8);

  float mrun[4], lrun[4];
  f32x4 o[8];
#pragma unroll
  for (int j = 0; j < 4; ++j) { mrun[j] = -1e30f; lrun[j] = 0.f; }
#pragma unroll
  for (int f = 0; f < 8; ++f) o[f] = (f32x4){0.f, 0.f, 0.f, 0.f};

  unsigned short* pw = &plds[wave][0];
  const int ntw = ((qbase + 15) >> 5) + 1;   // causal: last kv tile this wave needs

  for (int t = 0; t < ntw; ++t) {
    const int k0 = t * 32;
    f32x4 s0 = (f32x4){0.f, 0.f, 0.f, 0.f}, s1 = s0;
#pragma unroll
    for (int kk = 0; kk < 4; ++kk) {
      bf16x8 b0 = load8(Kb + (size_t)(k0 + ll) * HD_DIM + kk * 32 + lg * 8);
      bf16x8 b1 = load8(Kb + (size_t)(k0 + 16 + ll) * HD_DIM + kk * 32 + lg * 8);
      s0 = mfma_bf16(aq[kk], b0, s0);
      s1 = mfma_bf16(aq[kk], b1, s1);
    }
#pragma unroll
    for (int j = 0; j < 4; ++j) {
      int qrow = qbase + lg * 4 + j;
      float v0 = s0[j] * scale; if (k0 + ll      > qrow) v0 = -1e30f;
      float v1 = s1[j] * scale; if (k0 + 16 + ll > qrow) v1 = -1e30f;
      float mt = fmaxf(v0, v1);
#pragma unroll
      for (int off = 1; off < 16; off <<= 1) mt = fmaxf(mt, __shfl_xor(mt, off, 64));
      float mnew = fmaxf(mrun[j], mt);
      float corr = __expf(mrun[j] - mnew);
      float e0 = __expf(v0 - mnew);
      float e1 = __expf(v1 - mnew);
      float rs = e0 + e1;
#pragma unroll
      for (int off = 1; off < 16; off <<= 1) rs += __shfl_xor(rs, off, 64);
      lrun[j] = lrun[j] * corr + rs;
      mrun[j] = mnew;
#pragma unroll
      for (int f = 0; f < 8; ++f) o[f][j] *= corr;
      pw[(lg * 4 + j) * 40 + ll]      = f2bf(e0);
      pw[(lg * 4 + j) * 40 + 16 + ll] = f2bf(e1);
    }
    // P A-frag: row = lane&15, k = (lane>>4)*8 + i  (wave-local RAW through LDS)
    bf16x8 pa = load8(&pw[ll * 40 + lg * 8]);
#pragma unroll
    for (int f = 0; f < 8; ++f) {
      bf16x8 bv = load8(Vb + (size_t)(f * 16 + ll) * S_DIM + k0 + lg * 8);
      o[f] = mfma_bf16(pa, bv, o[f]);
    }
  }

#pragma unroll
  for (int f = 0; f < 8; ++f)
#pragma unroll
    for (int j = 0; j < 4; ++j) {
      int srow = qbase + lg * 4 + j;
      float val = o[f][j] / lrun[j];
      out[((size_t)(b * S_DIM + srow)) * H_DIM + h * HD_DIM + f * 16 + ll] = f2bf(val);
    }
}

// ---------------------------------------------------------------- launch
extern "C" void kernel_launch(void* const* d_in, const int* in_sizes, int n_in,
                              void* d_out, int out_size, void* d_ws, size_t ws_size,
                              hipStream_t stream) {
  (void)in_sizes; (void)n_in; (void)out_size; (void)ws_size;
  const float* hidden = (const float*)d_in[0];
  const float* wqkv   = (const float*)d_in[1];
  const float* wo     = (const float*)d_in[2];
  char* ws = (char*)d_ws;
  // workspace layout (needs ~161 MiB)
  unsigned short* hid_b  = (unsigned short*)(ws);               // 16,777,216
  unsigned short* wqkv_b = (unsigned short*)(ws + 16777216);    // 25,165,824
  unsigned short* wo_b   = (unsigned short*)(ws + 41943040);    //  8,388,608
  unsigned short* mixed  = (unsigned short*)(ws + 50331648);    // 50,331,648
  unsigned short* q_r    = (unsigned short*)(ws + 100663296);   // 16,777,216
  unsigned short* k_r    = (unsigned short*)(ws + 117440512);   // 16,777,216
  unsigned short* v_t    = (unsigned short*)(ws + 134217728);   // 16,777,216
  unsigned short* attn   = (unsigned short*)(ws + 150994944);   // 16,777,216
  float* cosT            = (float*)(ws + 167772160);            //    524,288
  float* sinT            = (float*)(ws + 168296448);            //    524,288

  cvt_kernel<<<1024, 256, 0, stream>>>(hidden, hid_b, BS * H_DIM / 4);
  cvt_kernel<<<1024, 256, 0, stream>>>(wqkv, wqkv_b, O3 * H_DIM / 4);
  cvt_kernel<<<1024, 256, 0, stream>>>(wo, wo_b, H_DIM * H_DIM / 4);
  rope_table_kernel<<<S_DIM * 64 / 256, 256, 0, stream>>>(cosT, sinT);

  gemm_bt_kernel<true><<<dim3(O3 / 128, BS / 128), 256, 0, stream>>>(
      hid_b, wqkv_b, mixed, BS, O3, H_DIM);

  rope_qk_kernel<<<BS, 256, 0, stream>>>(mixed, cosT, sinT, q_r, k_r);
  vtrans_kernel<<<dim3(32, 2, 32), 256, 0, stream>>>(mixed, v_t);

  attn_kernel<<<dim3(32, 32), 256, 0, stream>>>(q_r, k_r, v_t, attn);

  gemm_bt_kernel<false><<<dim3(H_DIM / 128, BS / 128), 256, 0, stream>>>(
      attn, wo_b, d_out, BS, H_DIM, H_DIM);
}

// Round 4
// 404.760 us; speedup vs baseline: 1.6246x; 1.6246x over previous
//
#include <hip/hip_runtime.h>
#include <hip/hip_bf16.h>
#include <cstdint>
#include <cstddef>

// Problem constants
#define S_DIM 2048
#define H_DIM 2048
#define NHEAD 16
#define HD_DIM 128
#define O3    6144   // 3*H
#define BS    4096   // B*S
#define NBH   32     // B*NHEAD

typedef short  s16x8  __attribute__((ext_vector_type(8)));
typedef __bf16 bf16x8 __attribute__((ext_vector_type(8)));
typedef float  f32x4  __attribute__((ext_vector_type(4)));

__device__ __forceinline__ unsigned short f2bf(float f) {
  unsigned int b = __float_as_uint(f);
  b += 0x7FFFu + ((b >> 16) & 1u);          // round-to-nearest-even
  return (unsigned short)(b >> 16);
}
__device__ __forceinline__ float bf2f(unsigned short u) {
  return __uint_as_float(((unsigned int)u) << 16);
}
__device__ __forceinline__ bf16x8 load8(const unsigned short* p) {
  s16x8 r = *(const s16x8*)p;
  return __builtin_bit_cast(bf16x8, r);
}
__device__ __forceinline__ f32x4 mfma_bf16(bf16x8 a, bf16x8 b, f32x4 c) {
  return __builtin_amdgcn_mfma_f32_16x16x32_bf16(a, b, c, 0, 0, 0);
}
__device__ __forceinline__ void gload_lds16(const void* g, void* l) {
  __builtin_amdgcn_global_load_lds(
      (__attribute__((address_space(1))) unsigned int*)g,
      (__attribute__((address_space(3))) unsigned int*)l, 16, 0, 0);
}

// ---------------------------------------------------------------- fp32 -> bf16
__global__ void cvt_kernel(const float* __restrict__ src,
                           unsigned short* __restrict__ dst, int n4) {
  int i = blockIdx.x * blockDim.x + threadIdx.x;
  int stride = gridDim.x * blockDim.x;
  for (; i < n4; i += stride) {
    float4 v = ((const float4*)src)[i];
    ushort4 o;
    o.x = f2bf(v.x); o.y = f2bf(v.y); o.z = f2bf(v.z); o.w = f2bf(v.w);
    ((ushort4*)dst)[i] = o;
  }
}

// ---------------------------------------------------------------- RoPE table
__global__ void rope_table_kernel(float* __restrict__ cosT,
                                  float* __restrict__ sinT) {
  int idx = blockIdx.x * blockDim.x + threadIdx.x;   // S_DIM*64 exactly
  int s = idx >> 6, d = idx & 63;
  float inv = expf(-((float)d / 64.0f) * 9.210340371976184f);
  float ang = (float)s * inv;
  float sn, cs;
  sincosf(ang, &sn, &cs);
  cosT[idx] = cs;
  sinT[idx] = sn;
}

// ---------------------------------------------------------------- GEMM (B^T)
// C[M][N] = A[M][K] * Bw[N][K]^T, all bf16 inputs; C fp32 or bf16.
// 128x128 tile, BK=64, 4 waves (2x2), each wave 64x64 = 4x4 16x16x32 frags.
template <bool OUT_BF16>
__global__ __launch_bounds__(256, 2)
void gemm_bt_kernel(const unsigned short* __restrict__ A,
                    const unsigned short* __restrict__ Bw,
                    void* __restrict__ C, int M, int N, int K) {
  __shared__ unsigned short lA[128 * 64];
  __shared__ unsigned short lB[128 * 64];
  const int tid  = threadIdx.x;
  const int wave = tid >> 6, lane = tid & 63;
  const int wy = wave >> 1, wx = wave & 1;
  const int lg = lane >> 4, ll = lane & 15;
  const int m0 = blockIdx.y * 128, n0 = blockIdx.x * 128;

  f32x4 acc[4][4];
#pragma unroll
  for (int i = 0; i < 4; ++i)
#pragma unroll
    for (int j = 0; j < 4; ++j) acc[i][j] = (f32x4){0.f, 0.f, 0.f, 0.f};

  for (int kt = 0; kt < K; kt += 64) {
    if (kt) __syncthreads();
#pragma unroll
    for (int i = 0; i < 4; ++i) {
      int cb = (i * 4 + wave) * 64;       // wave-uniform chunk base
      int c  = cb + lane;
      int r  = c >> 3, kc = c & 7;
      gload_lds16(A  + (size_t)(m0 + r) * K + kt + kc * 8, &lA[cb * 8]);
      gload_lds16(Bw + (size_t)(n0 + r) * K + kt + kc * 8, &lB[cb * 8]);
    }
    __syncthreads();
#pragma unroll
    for (int kk = 0; kk < 2; ++kk) {
      bf16x8 af[4], bfr[4];
#pragma unroll
      for (int f = 0; f < 4; ++f) {
        af[f]  = load8(&lA[(wy * 64 + f * 16 + ll) * 64 + kk * 32 + lg * 8]);
        bfr[f] = load8(&lB[(wx * 64 + f * 16 + ll) * 64 + kk * 32 + lg * 8]);
      }
#pragma unroll
      for (int fm = 0; fm < 4; ++fm)
#pragma unroll
        for (int fn = 0; fn < 4; ++fn)
          acc[fm][fn] = mfma_bf16(af[fm], bfr[fn], acc[fm][fn]);
    }
  }

  const int rbase = m0 + wy * 64, cbase = n0 + wx * 64;
#pragma unroll
  for (int fm = 0; fm < 4; ++fm)
#pragma unroll
    for (int fn = 0; fn < 4; ++fn)
#pragma unroll
      for (int j = 0; j < 4; ++j) {
        int r   = rbase + fm * 16 + lg * 4 + j;
        int col = cbase + fn * 16 + ll;
        if (OUT_BF16)
          ((unsigned short*)C)[(size_t)r * N + col] = f2bf(acc[fm][fn][j]);
        else
          ((float*)C)[(size_t)r * N + col] = acc[fm][fn][j];
      }
}

// ---------------------------------------------------------------- RoPE q,k
__global__ void rope_qk_kernel(const unsigned short* __restrict__ mixed,
                               const float* __restrict__ cosT,
                               const float* __restrict__ sinT,
                               unsigned short* __restrict__ qr,
                               unsigned short* __restrict__ kr) {
  int m = blockIdx.x;              // 0..BS-1
  int s = m & (S_DIM - 1);
  int b = m >> 11;
  const unsigned short* row = mixed + (size_t)m * O3;
#pragma unroll
  for (int it = 0; it < 4; ++it) {
    int idx = it * 256 + threadIdx.x;   // 0..1023 = 16 heads * 64 d-pairs
    int h = idx >> 6, d = idx & 63;
    float c  = cosT[(s << 6) + d];
    float sn = sinT[(s << 6) + d];
    int base = h * 384;
    float q0 = bf2f(row[base + d]),       q1 = bf2f(row[base + 64 + d]);
    float k0 = bf2f(row[base + 128 + d]), k1 = bf2f(row[base + 192 + d]);
    size_t ob = ((size_t)(b * NHEAD + h) * S_DIM + s) * HD_DIM;
    qr[ob + d]      = f2bf(q0 * c - q1 * sn);
    qr[ob + 64 + d] = f2bf(q1 * c + q0 * sn);
    kr[ob + d]      = f2bf(k0 * c - k1 * sn);
    kr[ob + 64 + d] = f2bf(k1 * c + k0 * sn);
  }
}

// ---------------------------------------------------------------- V transpose
// v_t[bh][d][s] <- mixed[b*S+s][h*384+256+d]; 64x64 tiles via LDS.
__global__ __launch_bounds__(256)
void vtrans_kernel(const unsigned short* __restrict__ mixed,
                   unsigned short* __restrict__ vt) {
  __shared__ unsigned short t[64 * 65];
  int st = blockIdx.x, dt = blockIdx.y, bh = blockIdx.z;
  int b = bh >> 4, h = bh & 15;
  int s0 = st * 64, d0 = dt * 64;
  int tid = threadIdx.x;
#pragma unroll
  for (int it = 0; it < 2; ++it) {
    int c = it * 256 + tid;                 // 0..511
    int sl = c >> 3, dc = c & 7;
    const unsigned short* src =
        mixed + (size_t)(b * S_DIM + s0 + sl) * O3 + h * 384 + 256 + d0 + dc * 8;
    s16x8 v = *(const s16x8*)src;
#pragma unroll
    for (int i = 0; i < 8; ++i) t[(dc * 8 + i) * 65 + sl] = (unsigned short)v[i];
  }
  __syncthreads();
#pragma unroll
  for (int it = 0; it < 2; ++it) {
    int c = it * 256 + tid;
    int dl = c >> 3, sc = c & 7;
    s16x8 v;
#pragma unroll
    for (int i = 0; i < 8; ++i) v[i] = (short)t[dl * 65 + sc * 8 + i];
    *(s16x8*)(vt + ((size_t)bh * HD_DIM + d0 + dl) * S_DIM + s0 + sc * 8) = v;
  }
}

// ---------------------------------------------------------------- attention
// grid (qt=32, bh=32), 256 threads = 4 waves, 16 q-rows each (block = 64 rows).
// KV tiles of 32 staged in LDS (double-buffered, global_load_lds w=16, XOR
// swizzle via pre-swizzled source). Block-uniform tile count; online softmax.
__global__ __launch_bounds__(256, 4)
void attn_kernel(const unsigned short* __restrict__ qr,
                 const unsigned short* __restrict__ kr,
                 const unsigned short* __restrict__ vt,
                 unsigned short* __restrict__ out) {
  __shared__ unsigned short kbuf[2][32 * 128];   // 8KB per buf, rows=s (256B)
  __shared__ unsigned short vbuf[2][128 * 32];   // 8KB per buf, rows=d (64B)
  __shared__ unsigned short plds[4][16 * 40];    // per-wave P round-trip
  const int qt = blockIdx.x, bh = blockIdx.y;
  const int wave = threadIdx.x >> 6, lane = threadIdx.x & 63;
  const int b = bh >> 4, h = bh & 15;
  const int q0 = qt * 64;
  const int qbase = q0 + wave * 16;
  const int lg = lane >> 4, ll = lane & 15;
  const unsigned short* Qb = qr + (size_t)bh * S_DIM * HD_DIM;
  const unsigned short* Kb = kr + (size_t)bh * S_DIM * HD_DIM;
  const unsigned short* Vb = vt + (size_t)bh * HD_DIM * S_DIM;
  const float scale = 0.08838834764831845f;  // 1/sqrt(128)
  const int ntb = 2 * qt + 2;                // block-uniform causal tile count

  // stage KV tile t into buf: 512 chunks K + 512 chunks V, 4 gload_lds/thread.
  // LDS dest is linear (wave-uniform base + lane*16); swizzle achieved by
  // permuting the per-lane GLOBAL source chunk (m173/G21).
  auto STAGE = [&](int buf, int t) {
    const int k0 = t * 32;
#pragma unroll
    for (int i = 0; i < 2; ++i) {
      int cb = (i * 4 + wave) * 64;          // 0..448, wave-uniform
      int c  = cb + lane;                    // K chunk 0..511
      int cs = c ^ ((c >> 4) & 7);           // K swizzle: row=c>>4 (16 chunks/row)
      gload_lds16(Kb + (size_t)(k0 + (cs >> 4)) * HD_DIM + (cs & 15) * 8,
                  &kbuf[buf][cb * 8]);
    }
#pragma unroll
    for (int i = 0; i < 2; ++i) {
      int cb = (i * 4 + wave) * 64;
      int c2 = cb + lane;                    // V chunk 0..511
      int cv = c2 ^ ((c2 >> 3) & 3);         // V swizzle: row=c2>>2 (4 chunks/row)
      gload_lds16(Vb + (size_t)(cv >> 2) * S_DIM + k0 + (cv & 3) * 8,
                  &vbuf[buf][cb * 8]);
    }
  };

  bf16x8 aq[4];
#pragma unroll
  for (int kk = 0; kk < 4; ++kk)
    aq[kk] = load8(Qb + (size_t)(qbase + ll) * HD_DIM + kk * 32 + lg * 8);

  float mrun[4], lrun[4];
  f32x4 o[8];
#pragma unroll
  for (int j = 0; j < 4; ++j) { mrun[j] = -1e30f; lrun[j] = 0.f; }
#pragma unroll
  for (int f = 0; f < 8; ++f) o[f] = (f32x4){0.f, 0.f, 0.f, 0.f};

  unsigned short* pw = &plds[wave][0];

  STAGE(0, 0);
  __syncthreads();   // implicit vmcnt(0) drain

  for (int t = 0; t < ntb; ++t) {
    const int cur = t & 1;
    if (t + 1 < ntb) STAGE(cur ^ 1, t + 1);   // issue next tile's loads early
    const int k0 = t * 32;

    // QK^T from swizzled K LDS: row r, byte (r*256 + kk*64 + lg*16) ^ ((r&7)<<4)
    f32x4 s0 = (f32x4){0.f, 0.f, 0.f, 0.f}, s1 = s0;
    const char* kb = (const char*)&kbuf[cur][0];
#pragma unroll
    for (int kk = 0; kk < 4; ++kk) {
      int r0 = ll, r1 = 16 + ll;
      int a0 = (r0 * 256 + kk * 64 + lg * 16) ^ ((r0 & 7) << 4);
      int a1 = (r1 * 256 + kk * 64 + lg * 16) ^ ((r1 & 7) << 4);
      bf16x8 b0 = load8((const unsigned short*)(kb + a0));
      bf16x8 b1 = load8((const unsigned short*)(kb + a1));
      s0 = mfma_bf16(aq[kk], b0, s0);
      s1 = mfma_bf16(aq[kk], b1, s1);
    }

#pragma unroll
    for (int j = 0; j < 4; ++j) {
      int qrow = qbase + lg * 4 + j;
      bool msk0 = (k0 + ll) > qrow;
      bool msk1 = (k0 + 16 + ll) > qrow;
      float v0 = msk0 ? -1e30f : s0[j] * scale;
      float v1 = msk1 ? -1e30f : s1[j] * scale;
      float mt = fmaxf(v0, v1);
#pragma unroll
      for (int off = 1; off < 16; off <<= 1) mt = fmaxf(mt, __shfl_xor(mt, off, 64));
      float mnew = fmaxf(mrun[j], mt);
      float corr = __expf(mrun[j] - mnew);
      // explicit zero for masked lanes: fully-masked tiles would otherwise
      // give exp(-1e30 - (-1e30)) = 1.
      float e0 = msk0 ? 0.f : __expf(v0 - mnew);
      float e1 = msk1 ? 0.f : __expf(v1 - mnew);
      float rs = e0 + e1;
#pragma unroll
      for (int off = 1; off < 16; off <<= 1) rs += __shfl_xor(rs, off, 64);
      lrun[j] = lrun[j] * corr + rs;
      mrun[j] = mnew;
#pragma unroll
      for (int f = 0; f < 8; ++f) o[f][j] *= corr;
      pw[(lg * 4 + j) * 40 + ll]      = f2bf(e0);
      pw[(lg * 4 + j) * 40 + 16 + ll] = f2bf(e1);
    }

    // P A-frag (wave-local LDS RAW), then PV from swizzled V LDS:
    // row r=d, byte (r*64 + lg*16) ^ (((r>>1)&3)<<4)
    bf16x8 pa = load8(&pw[ll * 40 + lg * 8]);
    const char* vb = (const char*)&vbuf[cur][0];
#pragma unroll
    for (int f = 0; f < 8; ++f) {
      int rv = f * 16 + ll;
      int av = (rv * 64 + lg * 16) ^ (((rv >> 1) & 3) << 4);
      bf16x8 bv = load8((const unsigned short*)(vb + av));
      o[f] = mfma_bf16(pa, bv, o[f]);
    }

    __syncthreads();   // drains vmcnt (next tile staged) + protects buffers
  }

#pragma unroll
  for (int f = 0; f < 8; ++f)
#pragma unroll
    for (int j = 0; j < 4; ++j) {
      int srow = qbase + lg * 4 + j;
      float val = o[f][j] / lrun[j];
      out[((size_t)(b * S_DIM + srow)) * H_DIM + h * HD_DIM + f * 16 + ll] = f2bf(val);
    }
}

// ---------------------------------------------------------------- launch
extern "C" void kernel_launch(void* const* d_in, const int* in_sizes, int n_in,
                              void* d_out, int out_size, void* d_ws, size_t ws_size,
                              hipStream_t stream) {
  (void)in_sizes; (void)n_in; (void)out_size; (void)ws_size;
  const float* hidden = (const float*)d_in[0];
  const float* wqkv   = (const float*)d_in[1];
  const float* wo     = (const float*)d_in[2];
  char* ws = (char*)d_ws;
  unsigned short* hid_b  = (unsigned short*)(ws);               // 16,777,216
  unsigned short* wqkv_b = (unsigned short*)(ws + 16777216);    // 25,165,824
  unsigned short* wo_b   = (unsigned short*)(ws + 41943040);    //  8,388,608
  unsigned short* mixed  = (unsigned short*)(ws + 50331648);    // 50,331,648
  unsigned short* q_r    = (unsigned short*)(ws + 100663296);   // 16,777,216
  unsigned short* k_r    = (unsigned short*)(ws + 117440512);   // 16,777,216
  unsigned short* v_t    = (unsigned short*)(ws + 134217728);   // 16,777,216
  unsigned short* attn   = (unsigned short*)(ws + 150994944);   // 16,777,216
  float* cosT            = (float*)(ws + 167772160);            //    524,288
  float* sinT            = (float*)(ws + 168296448);            //    524,288

  cvt_kernel<<<1024, 256, 0, stream>>>(hidden, hid_b, BS * H_DIM / 4);
  cvt_kernel<<<1024, 256, 0, stream>>>(wqkv, wqkv_b, O3 * H_DIM / 4);
  cvt_kernel<<<1024, 256, 0, stream>>>(wo, wo_b, H_DIM * H_DIM / 4);
  rope_table_kernel<<<S_DIM * 64 / 256, 256, 0, stream>>>(cosT, sinT);

  gemm_bt_kernel<true><<<dim3(O3 / 128, BS / 128), 256, 0, stream>>>(
      hid_b, wqkv_b, mixed, BS, O3, H_DIM);

  rope_qk_kernel<<<BS, 256, 0, stream>>>(mixed, cosT, sinT, q_r, k_r);
  vtrans_kernel<<<dim3(32, 2, 32), 256, 0, stream>>>(mixed, v_t);

  attn_kernel<<<dim3(32, 32), 256, 0, stream>>>(q_r, k_r, v_t, attn);

  gemm_bt_kernel<false><<<dim3(H_DIM / 128, BS / 128), 256, 0, stream>>>(
      attn, wo_b, d_out, BS, H_DIM, H_DIM);
}

// Round 5
// 337.636 us; speedup vs baseline: 1.9476x; 1.1988x over previous
//
#include <hip/hip_runtime.h>
#include <hip/hip_bf16.h>
#include <cstdint>
#include <cstddef>

// Problem constants
#define S_DIM 2048
#define H_DIM 2048
#define NHEAD 16
#define HD_DIM 128
#define O3    6144   // 3*H
#define BS    4096   // B*S
#define NBH   32     // B*NHEAD

typedef short  s16x8  __attribute__((ext_vector_type(8)));
typedef __bf16 bf16x8 __attribute__((ext_vector_type(8)));
typedef float  f32x4  __attribute__((ext_vector_type(4)));

__device__ __forceinline__ unsigned short f2bf(float f) {
  unsigned int b = __float_as_uint(f);
  b += 0x7FFFu + ((b >> 16) & 1u);          // round-to-nearest-even
  return (unsigned short)(b >> 16);
}
__device__ __forceinline__ float bf2f(unsigned short u) {
  return __uint_as_float(((unsigned int)u) << 16);
}
__device__ __forceinline__ bf16x8 load8(const unsigned short* p) {
  s16x8 r = *(const s16x8*)p;
  return __builtin_bit_cast(bf16x8, r);
}
__device__ __forceinline__ f32x4 mfma_bf16(bf16x8 a, bf16x8 b, f32x4 c) {
  return __builtin_amdgcn_mfma_f32_16x16x32_bf16(a, b, c, 0, 0, 0);
}
__device__ __forceinline__ void gload_lds16(const void* g, void* l) {
  __builtin_amdgcn_global_load_lds(
      (__attribute__((address_space(1))) unsigned int*)g,
      (__attribute__((address_space(3))) unsigned int*)l, 16, 0, 0);
}

// ---------------------------------------------------------------- fp32 -> bf16
__global__ void cvt_kernel(const float* __restrict__ src,
                           unsigned short* __restrict__ dst, int n4) {
  int i = blockIdx.x * blockDim.x + threadIdx.x;
  int stride = gridDim.x * blockDim.x;
  for (; i < n4; i += stride) {
    float4 v = ((const float4*)src)[i];
    ushort4 o;
    o.x = f2bf(v.x); o.y = f2bf(v.y); o.z = f2bf(v.z); o.w = f2bf(v.w);
    ((ushort4*)dst)[i] = o;
  }
}

// ---------------------------------------------------------------- RoPE table
__global__ void rope_table_kernel(float* __restrict__ cosT,
                                  float* __restrict__ sinT) {
  int idx = blockIdx.x * blockDim.x + threadIdx.x;   // S_DIM*64 exactly
  int s = idx >> 6, d = idx & 63;
  float inv = expf(-((float)d / 64.0f) * 9.210340371976184f);
  float ang = (float)s * inv;
  float sn, cs;
  sincosf(ang, &sn, &cs);
  cosT[idx] = cs;
  sinT[idx] = sn;
}

// ---------------------------------------------------------------- GEMM (B^T)
// C[M][N] = A[M][K] * Bw[N][K]^T, all bf16 inputs; C fp32 or bf16.
// 128x128 tile, BK=64, 4 waves (2x2), each wave 64x64 = 4x4 16x16x32 frags.
template <bool OUT_BF16>
__global__ __launch_bounds__(256, 2)
void gemm_bt_kernel(const unsigned short* __restrict__ A,
                    const unsigned short* __restrict__ Bw,
                    void* __restrict__ C, int M, int N, int K) {
  __shared__ unsigned short lA[128 * 64];
  __shared__ unsigned short lB[128 * 64];
  const int tid  = threadIdx.x;
  const int wave = tid >> 6, lane = tid & 63;
  const int wy = wave >> 1, wx = wave & 1;
  const int lg = lane >> 4, ll = lane & 15;
  const int m0 = blockIdx.y * 128, n0 = blockIdx.x * 128;

  f32x4 acc[4][4];
#pragma unroll
  for (int i = 0; i < 4; ++i)
#pragma unroll
    for (int j = 0; j < 4; ++j) acc[i][j] = (f32x4){0.f, 0.f, 0.f, 0.f};

  for (int kt = 0; kt < K; kt += 64) {
    if (kt) __syncthreads();
#pragma unroll
    for (int i = 0; i < 4; ++i) {
      int cb = (i * 4 + wave) * 64;       // wave-uniform chunk base
      int c  = cb + lane;
      int r  = c >> 3, kc = c & 7;
      gload_lds16(A  + (size_t)(m0 + r) * K + kt + kc * 8, &lA[cb * 8]);
      gload_lds16(Bw + (size_t)(n0 + r) * K + kt + kc * 8, &lB[cb * 8]);
    }
    __syncthreads();
#pragma unroll
    for (int kk = 0; kk < 2; ++kk) {
      bf16x8 af[4], bfr[4];
#pragma unroll
      for (int f = 0; f < 4; ++f) {
        af[f]  = load8(&lA[(wy * 64 + f * 16 + ll) * 64 + kk * 32 + lg * 8]);
        bfr[f] = load8(&lB[(wx * 64 + f * 16 + ll) * 64 + kk * 32 + lg * 8]);
      }
#pragma unroll
      for (int fm = 0; fm < 4; ++fm)
#pragma unroll
        for (int fn = 0; fn < 4; ++fn)
          acc[fm][fn] = mfma_bf16(af[fm], bfr[fn], acc[fm][fn]);
    }
  }

  const int rbase = m0 + wy * 64, cbase = n0 + wx * 64;
#pragma unroll
  for (int fm = 0; fm < 4; ++fm)
#pragma unroll
    for (int fn = 0; fn < 4; ++fn)
#pragma unroll
      for (int j = 0; j < 4; ++j) {
        int r   = rbase + fm * 16 + lg * 4 + j;
        int col = cbase + fn * 16 + ll;
        if (OUT_BF16)
          ((unsigned short*)C)[(size_t)r * N + col] = f2bf(acc[fm][fn][j]);
        else
          ((float*)C)[(size_t)r * N + col] = acc[fm][fn][j];
      }
}

// ---------------------------------------------------------------- RoPE q,k
__global__ void rope_qk_kernel(const unsigned short* __restrict__ mixed,
                               const float* __restrict__ cosT,
                               const float* __restrict__ sinT,
                               unsigned short* __restrict__ qr,
                               unsigned short* __restrict__ kr) {
  int m = blockIdx.x;              // 0..BS-1
  int s = m & (S_DIM - 1);
  int b = m >> 11;
  const unsigned short* row = mixed + (size_t)m * O3;
#pragma unroll
  for (int it = 0; it < 4; ++it) {
    int idx = it * 256 + threadIdx.x;   // 0..1023 = 16 heads * 64 d-pairs
    int h = idx >> 6, d = idx & 63;
    float c  = cosT[(s << 6) + d];
    float sn = sinT[(s << 6) + d];
    int base = h * 384;
    float q0 = bf2f(row[base + d]),       q1 = bf2f(row[base + 64 + d]);
    float k0 = bf2f(row[base + 128 + d]), k1 = bf2f(row[base + 192 + d]);
    size_t ob = ((size_t)(b * NHEAD + h) * S_DIM + s) * HD_DIM;
    qr[ob + d]      = f2bf(q0 * c - q1 * sn);
    qr[ob + 64 + d] = f2bf(q1 * c + q0 * sn);
    kr[ob + d]      = f2bf(k0 * c - k1 * sn);
    kr[ob + 64 + d] = f2bf(k1 * c + k0 * sn);
  }
}

// ---------------------------------------------------------------- V transpose
// v_t[bh][d][s] <- mixed[b*S+s][h*384+256+d]; 64x64 tiles via LDS.
__global__ __launch_bounds__(256)
void vtrans_kernel(const unsigned short* __restrict__ mixed,
                   unsigned short* __restrict__ vt) {
  __shared__ unsigned short t[64 * 65];
  int st = blockIdx.x, dt = blockIdx.y, bh = blockIdx.z;
  int b = bh >> 4, h = bh & 15;
  int s0 = st * 64, d0 = dt * 64;
  int tid = threadIdx.x;
#pragma unroll
  for (int it = 0; it < 2; ++it) {
    int c = it * 256 + tid;                 // 0..511
    int sl = c >> 3, dc = c & 7;
    const unsigned short* src =
        mixed + (size_t)(b * S_DIM + s0 + sl) * O3 + h * 384 + 256 + d0 + dc * 8;
    s16x8 v = *(const s16x8*)src;
#pragma unroll
    for (int i = 0; i < 8; ++i) t[(dc * 8 + i) * 65 + sl] = (unsigned short)v[i];
  }
  __syncthreads();
#pragma unroll
  for (int it = 0; it < 2; ++it) {
    int c = it * 256 + tid;
    int dl = c >> 3, sc = c & 7;
    s16x8 v;
#pragma unroll
    for (int i = 0; i < 8; ++i) v[i] = (short)t[dl * 65 + sc * 8 + i];
    *(s16x8*)(vt + ((size_t)bh * HD_DIM + d0 + dl) * S_DIM + s0 + sc * 8) = v;
  }
}

// ---------------------------------------------------------------- attention
// grid (p=16, bh=32), 256 threads = 4 waves, 16 q-rows each (seg = 64 rows).
// Perfect load balance: block p processes q-tiles {p, 31-p} sequentially ->
// (2p+2) + (64-2p) = 66 kv-tiles for EVERY block (512 blocks, 2/CU).
// KV tiles of 32 staged in LDS (double-buffered, global_load_lds w=16, XOR
// swizzle via pre-swizzled source). Block-uniform tile count; online softmax.
__global__ __launch_bounds__(256, 2)
void attn_kernel(const unsigned short* __restrict__ qr,
                 const unsigned short* __restrict__ kr,
                 const unsigned short* __restrict__ vt,
                 unsigned short* __restrict__ out) {
  __shared__ unsigned short kbuf[2][32 * 128];   // 8KB per buf, rows=s (256B)
  __shared__ unsigned short vbuf[2][128 * 32];   // 8KB per buf, rows=d (64B)
  __shared__ unsigned short plds[4][16 * 40];    // per-wave P round-trip
  const int p = blockIdx.x, bh = blockIdx.y;
  const int wave = threadIdx.x >> 6, lane = threadIdx.x & 63;
  const int b = bh >> 4, h = bh & 15;
  const int lg = lane >> 4, ll = lane & 15;
  const unsigned short* Qb = qr + (size_t)bh * S_DIM * HD_DIM;
  const unsigned short* Kb = kr + (size_t)bh * S_DIM * HD_DIM;
  const unsigned short* Vb = vt + (size_t)bh * HD_DIM * S_DIM;
  const float scale = 0.08838834764831845f;  // 1/sqrt(128)
  unsigned short* pw = &plds[wave][0];

  for (int seg = 0; seg < 2; ++seg) {
    const int qt = seg ? (31 - p) : p;
    const int q0 = qt * 64;
    const int qbase = q0 + wave * 16;
    const int ntb = 2 * qt + 2;              // block-uniform causal tile count

    // stage KV tile t into buf: 512 chunks K + 512 chunks V, 4 gload/thread.
    // LDS dest is linear (wave-uniform base + lane*16); swizzle achieved by
    // permuting the per-lane GLOBAL source chunk (m173/G21).
    auto STAGE = [&](int buf, int t) {
      const int k0 = t * 32;
#pragma unroll
      for (int i = 0; i < 2; ++i) {
        int cb = (i * 4 + wave) * 64;        // 0..448, wave-uniform
        int c  = cb + lane;                  // K chunk 0..511
        int cs = c ^ ((c >> 4) & 7);         // K swizzle: row=c>>4
        gload_lds16(Kb + (size_t)(k0 + (cs >> 4)) * HD_DIM + (cs & 15) * 8,
                    &kbuf[buf][cb * 8]);
      }
#pragma unroll
      for (int i = 0; i < 2; ++i) {
        int cb = (i * 4 + wave) * 64;
        int c2 = cb + lane;                  // V chunk 0..511
        int cv = c2 ^ ((c2 >> 3) & 3);       // V swizzle: row=c2>>2
        gload_lds16(Vb + (size_t)(cv >> 2) * S_DIM + k0 + (cv & 3) * 8,
                    &vbuf[buf][cb * 8]);
      }
    };

    bf16x8 aq[4];
#pragma unroll
    for (int kk = 0; kk < 4; ++kk)
      aq[kk] = load8(Qb + (size_t)(qbase + ll) * HD_DIM + kk * 32 + lg * 8);

    float mrun[4], lrun[4];
    f32x4 o[8];
#pragma unroll
    for (int j = 0; j < 4; ++j) { mrun[j] = -1e30f; lrun[j] = 0.f; }
#pragma unroll
    for (int f = 0; f < 8; ++f) o[f] = (f32x4){0.f, 0.f, 0.f, 0.f};

    STAGE(0, 0);
    __syncthreads();   // implicit vmcnt(0) drain

    for (int t = 0; t < ntb; ++t) {
      const int cur = t & 1;
      if (t + 1 < ntb) STAGE(cur ^ 1, t + 1);   // issue next tile's loads early
      const int k0 = t * 32;

      // QK^T from swizzled K LDS: row r, byte (r*256+kk*64+lg*16)^((r&7)<<4)
      f32x4 s0 = (f32x4){0.f, 0.f, 0.f, 0.f}, s1 = s0;
      const char* kb = (const char*)&kbuf[cur][0];
#pragma unroll
      for (int kk = 0; kk < 4; ++kk) {
        int r0 = ll, r1 = 16 + ll;
        int a0 = (r0 * 256 + kk * 64 + lg * 16) ^ ((r0 & 7) << 4);
        int a1 = (r1 * 256 + kk * 64 + lg * 16) ^ ((r1 & 7) << 4);
        bf16x8 b0 = load8((const unsigned short*)(kb + a0));
        bf16x8 b1 = load8((const unsigned short*)(kb + a1));
        s0 = mfma_bf16(aq[kk], b0, s0);
        s1 = mfma_bf16(aq[kk], b1, s1);
      }

#pragma unroll
      for (int j = 0; j < 4; ++j) {
        int qrow = qbase + lg * 4 + j;
        bool msk0 = (k0 + ll) > qrow;
        bool msk1 = (k0 + 16 + ll) > qrow;
        float v0 = msk0 ? -1e30f : s0[j] * scale;
        float v1 = msk1 ? -1e30f : s1[j] * scale;
        float mt = fmaxf(v0, v1);
#pragma unroll
        for (int off = 1; off < 16; off <<= 1) mt = fmaxf(mt, __shfl_xor(mt, off, 64));
        float mnew = fmaxf(mrun[j], mt);
        float corr = __expf(mrun[j] - mnew);
        // explicit zero for masked lanes: fully-masked tiles would otherwise
        // give exp(-1e30 - (-1e30)) = 1.
        float e0 = msk0 ? 0.f : __expf(v0 - mnew);
        float e1 = msk1 ? 0.f : __expf(v1 - mnew);
        float rs = e0 + e1;
#pragma unroll
        for (int off = 1; off < 16; off <<= 1) rs += __shfl_xor(rs, off, 64);
        lrun[j] = lrun[j] * corr + rs;
        mrun[j] = mnew;
#pragma unroll
        for (int f = 0; f < 8; ++f) o[f][j] *= corr;
        pw[(lg * 4 + j) * 40 + ll]      = f2bf(e0);
        pw[(lg * 4 + j) * 40 + 16 + ll] = f2bf(e1);
      }

      // P A-frag (wave-local LDS RAW), then PV from swizzled V LDS:
      // row r=d, byte (r*64 + lg*16) ^ (((r>>1)&3)<<4)
      bf16x8 pa = load8(&pw[ll * 40 + lg * 8]);
      const char* vb = (const char*)&vbuf[cur][0];
#pragma unroll
      for (int f = 0; f < 8; ++f) {
        int rv = f * 16 + ll;
        int av = (rv * 64 + lg * 16) ^ (((rv >> 1) & 3) << 4);
        bf16x8 bv = load8((const unsigned short*)(vb + av));
        o[f] = mfma_bf16(pa, bv, o[f]);
      }

      __syncthreads();   // drains vmcnt (next tile staged) + protects buffers
    }

#pragma unroll
    for (int f = 0; f < 8; ++f)
#pragma unroll
      for (int j = 0; j < 4; ++j) {
        int srow = qbase + lg * 4 + j;
        float val = o[f][j] / lrun[j];
        out[((size_t)(b * S_DIM + srow)) * H_DIM + h * HD_DIM + f * 16 + ll] =
            f2bf(val);
      }
    // no extra barrier needed: last t-loop iteration ended with __syncthreads,
    // epilogue touches no LDS, so next segment's STAGE(0,0) is safe.
  }
}

// ---------------------------------------------------------------- launch
extern "C" void kernel_launch(void* const* d_in, const int* in_sizes, int n_in,
                              void* d_out, int out_size, void* d_ws, size_t ws_size,
                              hipStream_t stream) {
  (void)in_sizes; (void)n_in; (void)out_size; (void)ws_size;
  const float* hidden = (const float*)d_in[0];
  const float* wqkv   = (const float*)d_in[1];
  const float* wo     = (const float*)d_in[2];
  char* ws = (char*)d_ws;
  unsigned short* hid_b  = (unsigned short*)(ws);               // 16,777,216
  unsigned short* wqkv_b = (unsigned short*)(ws + 16777216);    // 25,165,824
  unsigned short* wo_b   = (unsigned short*)(ws + 41943040);    //  8,388,608
  unsigned short* mixed  = (unsigned short*)(ws + 50331648);    // 50,331,648
  unsigned short* q_r    = (unsigned short*)(ws + 100663296);   // 16,777,216
  unsigned short* k_r    = (unsigned short*)(ws + 117440512);   // 16,777,216
  unsigned short* v_t    = (unsigned short*)(ws + 134217728);   // 16,777,216
  unsigned short* attn   = (unsigned short*)(ws + 150994944);   // 16,777,216
  float* cosT            = (float*)(ws + 167772160);            //    524,288
  float* sinT            = (float*)(ws + 168296448);            //    524,288

  cvt_kernel<<<1024, 256, 0, stream>>>(hidden, hid_b, BS * H_DIM / 4);
  cvt_kernel<<<1024, 256, 0, stream>>>(wqkv, wqkv_b, O3 * H_DIM / 4);
  cvt_kernel<<<1024, 256, 0, stream>>>(wo, wo_b, H_DIM * H_DIM / 4);
  rope_table_kernel<<<S_DIM * 64 / 256, 256, 0, stream>>>(cosT, sinT);

  gemm_bt_kernel<true><<<dim3(O3 / 128, BS / 128), 256, 0, stream>>>(
      hid_b, wqkv_b, mixed, BS, O3, H_DIM);

  rope_qk_kernel<<<BS, 256, 0, stream>>>(mixed, cosT, sinT, q_r, k_r);
  vtrans_kernel<<<dim3(32, 2, 32), 256, 0, stream>>>(mixed, v_t);

  attn_kernel<<<dim3(16, 32), 256, 0, stream>>>(q_r, k_r, v_t, attn);

  gemm_bt_kernel<false><<<dim3(H_DIM / 128, BS / 128), 256, 0, stream>>>(
      attn, wo_b, d_out, BS, H_DIM, H_DIM);
}

// Round 6
// 299.974 us; speedup vs baseline: 2.1921x; 1.1256x over previous
//
#include <hip/hip_runtime.h>
#include <hip/hip_bf16.h>
#include <cstdint>
#include <cstddef>

// Problem constants
#define S_DIM 2048
#define H_DIM 2048
#define NHEAD 16
#define HD_DIM 128
#define O3    6144   // 3*H
#define BS    4096   // B*S
#define NBH   32     // B*NHEAD

typedef short  s16x8  __attribute__((ext_vector_type(8)));
typedef __bf16 bf16x8 __attribute__((ext_vector_type(8)));
typedef float  f32x4  __attribute__((ext_vector_type(4)));

__device__ __forceinline__ unsigned short f2bf(float f) {
  unsigned int b = __float_as_uint(f);
  b += 0x7FFFu + ((b >> 16) & 1u);          // round-to-nearest-even
  return (unsigned short)(b >> 16);
}
__device__ __forceinline__ float bf2f(unsigned short u) {
  return __uint_as_float(((unsigned int)u) << 16);
}
__device__ __forceinline__ bf16x8 load8(const unsigned short* p) {
  s16x8 r = *(const s16x8*)p;
  return __builtin_bit_cast(bf16x8, r);
}
__device__ __forceinline__ f32x4 mfma_bf16(bf16x8 a, bf16x8 b, f32x4 c) {
  return __builtin_amdgcn_mfma_f32_16x16x32_bf16(a, b, c, 0, 0, 0);
}
__device__ __forceinline__ void gload_lds16(const void* g, void* l) {
  __builtin_amdgcn_global_load_lds(
      (__attribute__((address_space(1))) unsigned int*)g,
      (__attribute__((address_space(3))) unsigned int*)l, 16, 0, 0);
}

// ---------------------------------------------------------------- fp32 -> bf16
__global__ void cvt_kernel(const float* __restrict__ src,
                           unsigned short* __restrict__ dst, int n4) {
  int i = blockIdx.x * blockDim.x + threadIdx.x;
  int stride = gridDim.x * blockDim.x;
  for (; i < n4; i += stride) {
    float4 v = ((const float4*)src)[i];
    ushort4 o;
    o.x = f2bf(v.x); o.y = f2bf(v.y); o.z = f2bf(v.z); o.w = f2bf(v.w);
    ((ushort4*)dst)[i] = o;
  }
}

// ---------------------------------------------------------------- RoPE table
__global__ void rope_table_kernel(float* __restrict__ cosT,
                                  float* __restrict__ sinT) {
  int idx = blockIdx.x * blockDim.x + threadIdx.x;   // S_DIM*64 exactly
  int s = idx >> 6, d = idx & 63;
  float inv = expf(-((float)d / 64.0f) * 9.210340371976184f);
  float ang = (float)s * inv;
  float sn, cs;
  sincosf(ang, &sn, &cs);
  cosT[idx] = cs;
  sinT[idx] = sn;
}

// ---------------------------------------------------------------- GEMM (B^T)
// C[M][N] = A[M][K] * Bw[N][K]^T, all bf16 inputs; C fp32 or bf16.
// 128x128 tile, BK=64, 4 waves (2x2), each wave 64x64 = 4x4 16x16x32 frags.
template <bool OUT_BF16>
__global__ __launch_bounds__(256, 2)
void gemm_bt_kernel(const unsigned short* __restrict__ A,
                    const unsigned short* __restrict__ Bw,
                    void* __restrict__ C, int M, int N, int K) {
  __shared__ unsigned short lA[128 * 64];
  __shared__ unsigned short lB[128 * 64];
  const int tid  = threadIdx.x;
  const int wave = tid >> 6, lane = tid & 63;
  const int wy = wave >> 1, wx = wave & 1;
  const int lg = lane >> 4, ll = lane & 15;
  const int m0 = blockIdx.y * 128, n0 = blockIdx.x * 128;

  f32x4 acc[4][4];
#pragma unroll
  for (int i = 0; i < 4; ++i)
#pragma unroll
    for (int j = 0; j < 4; ++j) acc[i][j] = (f32x4){0.f, 0.f, 0.f, 0.f};

  for (int kt = 0; kt < K; kt += 64) {
    if (kt) __syncthreads();
#pragma unroll
    for (int i = 0; i < 4; ++i) {
      int cb = (i * 4 + wave) * 64;       // wave-uniform chunk base
      int c  = cb + lane;
      int r  = c >> 3, kc = c & 7;
      gload_lds16(A  + (size_t)(m0 + r) * K + kt + kc * 8, &lA[cb * 8]);
      gload_lds16(Bw + (size_t)(n0 + r) * K + kt + kc * 8, &lB[cb * 8]);
    }
    __syncthreads();
#pragma unroll
    for (int kk = 0; kk < 2; ++kk) {
      bf16x8 af[4], bfr[4];
#pragma unroll
      for (int f = 0; f < 4; ++f) {
        af[f]  = load8(&lA[(wy * 64 + f * 16 + ll) * 64 + kk * 32 + lg * 8]);
        bfr[f] = load8(&lB[(wx * 64 + f * 16 + ll) * 64 + kk * 32 + lg * 8]);
      }
#pragma unroll
      for (int fm = 0; fm < 4; ++fm)
#pragma unroll
        for (int fn = 0; fn < 4; ++fn)
          acc[fm][fn] = mfma_bf16(af[fm], bfr[fn], acc[fm][fn]);
    }
  }

  const int rbase = m0 + wy * 64, cbase = n0 + wx * 64;
#pragma unroll
  for (int fm = 0; fm < 4; ++fm)
#pragma unroll
    for (int fn = 0; fn < 4; ++fn)
#pragma unroll
      for (int j = 0; j < 4; ++j) {
        int r   = rbase + fm * 16 + lg * 4 + j;
        int col = cbase + fn * 16 + ll;
        if (OUT_BF16)
          ((unsigned short*)C)[(size_t)r * N + col] = f2bf(acc[fm][fn][j]);
        else
          ((float*)C)[(size_t)r * N + col] = acc[fm][fn][j];
      }
}

// ---------------------------------------------------------------- RoPE q,k
__global__ void rope_qk_kernel(const unsigned short* __restrict__ mixed,
                               const float* __restrict__ cosT,
                               const float* __restrict__ sinT,
                               unsigned short* __restrict__ qr,
                               unsigned short* __restrict__ kr) {
  int m = blockIdx.x;              // 0..BS-1
  int s = m & (S_DIM - 1);
  int b = m >> 11;
  const unsigned short* row = mixed + (size_t)m * O3;
#pragma unroll
  for (int it = 0; it < 4; ++it) {
    int idx = it * 256 + threadIdx.x;   // 0..1023 = 16 heads * 64 d-pairs
    int h = idx >> 6, d = idx & 63;
    float c  = cosT[(s << 6) + d];
    float sn = sinT[(s << 6) + d];
    int base = h * 384;
    float q0 = bf2f(row[base + d]),       q1 = bf2f(row[base + 64 + d]);
    float k0 = bf2f(row[base + 128 + d]), k1 = bf2f(row[base + 192 + d]);
    size_t ob = ((size_t)(b * NHEAD + h) * S_DIM + s) * HD_DIM;
    qr[ob + d]      = f2bf(q0 * c - q1 * sn);
    qr[ob + 64 + d] = f2bf(q1 * c + q0 * sn);
    kr[ob + d]      = f2bf(k0 * c - k1 * sn);
    kr[ob + 64 + d] = f2bf(k1 * c + k0 * sn);
  }
}

// ---------------------------------------------------------------- V transpose
// v_t[bh][d][s] <- mixed[b*S+s][h*384+256+d]; 64x64 tiles via LDS.
__global__ __launch_bounds__(256)
void vtrans_kernel(const unsigned short* __restrict__ mixed,
                   unsigned short* __restrict__ vt) {
  __shared__ unsigned short t[64 * 65];
  int st = blockIdx.x, dt = blockIdx.y, bh = blockIdx.z;
  int b = bh >> 4, h = bh & 15;
  int s0 = st * 64, d0 = dt * 64;
  int tid = threadIdx.x;
#pragma unroll
  for (int it = 0; it < 2; ++it) {
    int c = it * 256 + tid;                 // 0..511
    int sl = c >> 3, dc = c & 7;
    const unsigned short* src =
        mixed + (size_t)(b * S_DIM + s0 + sl) * O3 + h * 384 + 256 + d0 + dc * 8;
    s16x8 v = *(const s16x8*)src;
#pragma unroll
    for (int i = 0; i < 8; ++i) t[(dc * 8 + i) * 65 + sl] = (unsigned short)v[i];
  }
  __syncthreads();
#pragma unroll
  for (int it = 0; it < 2; ++it) {
    int c = it * 256 + tid;
    int dl = c >> 3, sc = c & 7;
    s16x8 v;
#pragma unroll
    for (int i = 0; i < 8; ++i) v[i] = (short)t[dl * 65 + sc * 8 + i];
    *(s16x8*)(vt + ((size_t)bh * HD_DIM + d0 + dl) * S_DIM + s0 + sc * 8) = v;
  }
}

// ---------------------------------------------------------------- attention
// grid (p=16, bh=32), 256 threads = 4 waves, 16 q-rows each (seg = 64 rows).
// Balance: block p processes q-tiles {p, 31-p}: (p+1)+(32-p) = 33 kv64-tiles
// for every block. KVBLK=64 staged in LDS (dbuf, global_load_lds w=16, XOR
// swizzle via pre-swizzled source). Defer-max (T13): rescale branch ~once per
// segment; common path has zero shuffles. Masks only on the diagonal tile.
__global__ __launch_bounds__(256, 2)
void attn_kernel(const unsigned short* __restrict__ qr,
                 const unsigned short* __restrict__ kr,
                 const unsigned short* __restrict__ vt,
                 unsigned short* __restrict__ out) {
  __shared__ __align__(16) unsigned short kbuf[2][64 * 128]; // 16KB/buf rows=s
  __shared__ __align__(16) unsigned short vbuf[2][128 * 64]; // 16KB/buf rows=d
  __shared__ __align__(16) unsigned short plds[4][16 * 72];  // per-wave P
  const int p = blockIdx.x, bh = blockIdx.y;
  const int wave = threadIdx.x >> 6, lane = threadIdx.x & 63;
  const int b = bh >> 4, h = bh & 15;
  const int lg = lane >> 4, ll = lane & 15;
  const unsigned short* Qb = qr + (size_t)bh * S_DIM * HD_DIM;
  const unsigned short* Kb = kr + (size_t)bh * S_DIM * HD_DIM;
  const unsigned short* Vb = vt + (size_t)bh * HD_DIM * S_DIM;
  const float kE  = 0.12752792f;   // (1/sqrt(128)) * log2(e)
  const float THR = 11.5416f;      // 8 * log2(e)  (T13 threshold, k-domain)
  unsigned short* pw = &plds[wave][0];

  for (int seg = 0; seg < 2; ++seg) {
    const int qt = seg ? (31 - p) : p;
    const int qbase = qt * 64 + wave * 16;
    const int ntb = qt + 1;                // causal kv64-tile count

    // stage KV64 tile t: 1024 K chunks + 1024 V chunks, 8 gload/thread.
    // LDS dest linear; swizzle via permuted GLOBAL source chunk (m173/G21).
    auto STAGE = [&](int buf, int t) {
      const int k0 = t * 64;
#pragma unroll
      for (int i = 0; i < 4; ++i) {
        int cb = (i * 4 + wave) * 64;      // wave-uniform
        int c  = cb + lane;                // K chunk 0..1023 (16/row)
        int cs = c ^ ((c >> 4) & 7);
        gload_lds16(Kb + (size_t)(k0 + (cs >> 4)) * HD_DIM + (cs & 15) * 8,
                    &kbuf[buf][cb * 8]);
      }
#pragma unroll
      for (int i = 0; i < 4; ++i) {
        int cb = (i * 4 + wave) * 64;
        int c  = cb + lane;                // V chunk 0..1023 (8/row)
        int cv = c ^ ((c >> 3) & 7);
        gload_lds16(Vb + (size_t)(cv >> 3) * S_DIM + k0 + (cv & 7) * 8,
                    &vbuf[buf][cb * 8]);
      }
    };

    bf16x8 aq[4];
#pragma unroll
    for (int kk = 0; kk < 4; ++kk)
      aq[kk] = load8(Qb + (size_t)(qbase + ll) * HD_DIM + kk * 32 + lg * 8);

    float mk[4], lsum[4];
    f32x4 o[8];
#pragma unroll
    for (int j = 0; j < 4; ++j) { mk[j] = -1e30f; lsum[j] = 0.f; }
#pragma unroll
    for (int f = 0; f < 8; ++f) o[f] = (f32x4){0.f, 0.f, 0.f, 0.f};

    STAGE(0, 0);
    __syncthreads();   // implicit vmcnt(0) drain

    for (int t = 0; t < ntb; ++t) {
      const int cur = t & 1;
      if (t + 1 < ntb) STAGE(cur ^ 1, t + 1);  // overlap with this tile's work
      const int k0 = t * 64;
      const bool diag = (t == ntb - 1);        // block-uniform

      // ---- QK^T: s[kf] covers kv rows k0+kf*16..+16, K from swizzled LDS
      f32x4 s[4];
#pragma unroll
      for (int kf = 0; kf < 4; ++kf) s[kf] = (f32x4){0.f, 0.f, 0.f, 0.f};
      const char* kb = (const char*)&kbuf[cur][0];
      __builtin_amdgcn_s_setprio(1);
#pragma unroll
      for (int kf = 0; kf < 4; ++kf) {
        int r = kf * 16 + ll;
#pragma unroll
        for (int kk = 0; kk < 4; ++kk) {
          int a = (r * 256 + kk * 64 + lg * 16) ^ ((r & 7) << 4);
          s[kf] = mfma_bf16(aq[kk], load8((const unsigned short*)(kb + a)), s[kf]);
        }
      }
      __builtin_amdgcn_s_setprio(0);

      // ---- causal mask (diagonal tile only; raw-score domain)
      if (diag) {
#pragma unroll
        for (int kf = 0; kf < 4; ++kf) {
          int kcol = k0 + kf * 16 + ll;
#pragma unroll
          for (int j = 0; j < 4; ++j) {
            int qrow = qbase + lg * 4 + j;
            if (kcol > qrow) s[kf][j] = -1e31f;
          }
        }
      }

      // ---- defer-max online softmax (T13). mk is running max * kE.
      float pmax[4];
      bool ok = true;
#pragma unroll
      for (int j = 0; j < 4; ++j) {
        pmax[j] = fmaxf(fmaxf(s[0][j], s[1][j]), fmaxf(s[2][j], s[3][j]));
        ok = ok && (pmax[j] * kE - mk[j] <= THR);
      }
      if (!__all(ok)) {                      // rare: ~once per segment
#pragma unroll
        for (int j = 0; j < 4; ++j) {
          float rm = pmax[j] * kE;
#pragma unroll
          for (int off = 1; off < 16; off <<= 1)
            rm = fmaxf(rm, __shfl_xor(rm, off, 64));
          rm = fmaxf(rm, mk[j]);
          float corr = exp2f(mk[j] - rm);
          mk[j] = rm;
          lsum[j] *= corr;
#pragma unroll
          for (int f = 0; f < 8; ++f) o[f][j] *= corr;
        }
      }
      // P = exp2(s*kE - mk)  (bounded by 2^THR = e^8); per-lane l partials.
#pragma unroll
      for (int j = 0; j < 4; ++j) {
        int prow = (lg * 4 + j) * 72;
#pragma unroll
        for (int kf = 0; kf < 4; ++kf) {
          float e = exp2f(fmaf(s[kf][j], kE, -mk[j]));
          lsum[j] += e;
          pw[prow + kf * 16 + ll] = f2bf(e);
        }
      }

      // ---- PV from swizzled V LDS (P round-trip through per-wave LDS)
      bf16x8 pa0 = load8(&pw[ll * 72 + lg * 8]);
      bf16x8 pa1 = load8(&pw[ll * 72 + 32 + lg * 8]);
      const char* vb = (const char*)&vbuf[cur][0];
      __builtin_amdgcn_s_setprio(1);
#pragma unroll
      for (int f = 0; f < 8; ++f) {
        int rv = f * 16 + ll;
        int a0 = (rv * 128 + lg * 16) ^ ((rv & 7) << 4);
        int a1 = (rv * 128 + 64 + lg * 16) ^ ((rv & 7) << 4);
        o[f] = mfma_bf16(pa0, load8((const unsigned short*)(vb + a0)), o[f]);
        o[f] = mfma_bf16(pa1, load8((const unsigned short*)(vb + a1)), o[f]);
      }
      __builtin_amdgcn_s_setprio(0);

      __syncthreads();   // drains vmcnt (next tile staged) + protects buffers
    }

    // ---- epilogue: reduce l partials once, normalize, store
#pragma unroll
    for (int j = 0; j < 4; ++j) {
      float l = lsum[j];
#pragma unroll
      for (int off = 1; off < 16; off <<= 1) l += __shfl_xor(l, off, 64);
      lsum[j] = 1.0f / l;
    }
#pragma unroll
    for (int f = 0; f < 8; ++f)
#pragma unroll
      for (int j = 0; j < 4; ++j) {
        int srow = qbase + lg * 4 + j;
        out[((size_t)(b * S_DIM + srow)) * H_DIM + h * HD_DIM + f * 16 + ll] =
            f2bf(o[f][j] * lsum[j]);
      }
    // next segment's STAGE(0,0) is safe: last loop iter ended with barrier,
    // epilogue touches no LDS.
  }
}

// ---------------------------------------------------------------- launch
extern "C" void kernel_launch(void* const* d_in, const int* in_sizes, int n_in,
                              void* d_out, int out_size, void* d_ws, size_t ws_size,
                              hipStream_t stream) {
  (void)in_sizes; (void)n_in; (void)out_size; (void)ws_size;
  const float* hidden = (const float*)d_in[0];
  const float* wqkv   = (const float*)d_in[1];
  const float* wo     = (const float*)d_in[2];
  char* ws = (char*)d_ws;
  unsigned short* hid_b  = (unsigned short*)(ws);               // 16,777,216
  unsigned short* wqkv_b = (unsigned short*)(ws + 16777216);    // 25,165,824
  unsigned short* wo_b   = (unsigned short*)(ws + 41943040);    //  8,388,608
  unsigned short* mixed  = (unsigned short*)(ws + 50331648);    // 50,331,648
  unsigned short* q_r    = (unsigned short*)(ws + 100663296);   // 16,777,216
  unsigned short* k_r    = (unsigned short*)(ws + 117440512);   // 16,777,216
  unsigned short* v_t    = (unsigned short*)(ws + 134217728);   // 16,777,216
  unsigned short* attn   = (unsigned short*)(ws + 150994944);   // 16,777,216
  float* cosT            = (float*)(ws + 167772160);            //    524,288
  float* sinT            = (float*)(ws + 168296448);            //    524,288

  cvt_kernel<<<1024, 256, 0, stream>>>(hidden, hid_b, BS * H_DIM / 4);
  cvt_kernel<<<1024, 256, 0, stream>>>(wqkv, wqkv_b, O3 * H_DIM / 4);
  cvt_kernel<<<1024, 256, 0, stream>>>(wo, wo_b, H_DIM * H_DIM / 4);
  rope_table_kernel<<<S_DIM * 64 / 256, 256, 0, stream>>>(cosT, sinT);

  gemm_bt_kernel<true><<<dim3(O3 / 128, BS / 128), 256, 0, stream>>>(
      hid_b, wqkv_b, mixed, BS, O3, H_DIM);

  rope_qk_kernel<<<BS, 256, 0, stream>>>(mixed, cosT, sinT, q_r, k_r);
  vtrans_kernel<<<dim3(32, 2, 32), 256, 0, stream>>>(mixed, v_t);

  attn_kernel<<<dim3(16, 32), 256, 0, stream>>>(q_r, k_r, v_t, attn);

  gemm_bt_kernel<false><<<dim3(H_DIM / 128, BS / 128), 256, 0, stream>>>(
      attn, wo_b, d_out, BS, H_DIM, H_DIM);
}